// Round 3
// baseline (1016.227 us; speedup 1.0000x reference)
//
#include <hip/hip_runtime.h>
#include <cstdint>
#include <cstddef>

// HiPPO x_{k+1} = Ab x_k + b u_k, f[k]=x_{k+1}, L=65536, N=512.
// Chunked scan (C=16, G=4096): one big GEMM F(4096x8192)=Xcat(4096x544)@Wcat,
// chunk states via Blelloch sweep with on-device matrix powers.
// Numerics: chain/power matrices kept fp32, split to (hi,lo) f16 on the fly
// inside GEMM staging (Ootomo split, 2048 scale): effective ~22-bit mantissa.
// Workspace kept under 47 MB via overlays (round-2 failure = ws overflow).

typedef _Float16 half_t;
typedef _Float16 f16x8 __attribute__((ext_vector_type(8)));
typedef float f32x4 __attribute__((ext_vector_type(4)));

static constexpr int KPAD = 544;               // 512 + 16 u-taps + 16 pad
static constexpr size_t MSZ = (size_t)512 * 512;
static constexpr float INV2048 = 1.f / 2048.f;

__device__ inline void split1(float v, half_t& h, half_t& l) {
  h = (half_t)v;
  l = (half_t)((v - (float)h) * 2048.f);
}

// ---------------- utility kernels ----------------

__global__ void copy_ab_kernel(const float* __restrict__ Ab, float* __restrict__ V0) {
  int idx = blockIdx.x * 256 + threadIdx.x;    // 262144
  V0[idx] = Ab[idx];
}

__global__ void cast_x0_kernel(const float* __restrict__ x0, half_t* __restrict__ xh) {
  xh[threadIdx.x] = (half_t)x0[threadIdx.x];
}

// K[t,n] = (Ab^t b)[n], t=0..15 (fp32); V slot z = Ab^{z+1} (fp32)
__global__ void kbuild_kernel(const float* __restrict__ V, const float* __restrict__ b,
                              float* __restrict__ K) {
  int t = blockIdx.x, n = threadIdx.x;
  if (t == 0) { K[n] = b[n]; return; }
  const float* row = V + (size_t)(t - 1) * MSZ + (size_t)n * 512;
  float acc = 0.f;
  for (int m = 0; m < 512; ++m) acc += row[m] * b[m];
  K[t * 512 + n] = acc;
}

// WcatT[(i*512+n), k]: k<512 -> Ab^{i+1}[n,k]; 512+j -> (j<=i)?K[i-j,n]:0; pad 0
__global__ void wcat_fill_kernel(const float* __restrict__ V, const float* __restrict__ K,
                                 half_t* __restrict__ Wh, half_t* __restrict__ Wl) {
  size_t idx = (size_t)blockIdx.x * 256 + threadIdx.x;
  if (idx >= (size_t)8192 * KPAD) return;
  int row = (int)(idx / KPAD), k = (int)(idx % KPAD);
  int i = row >> 9, n = row & 511;
  float v = 0.f;
  if (k < 512) v = V[(size_t)i * MSZ + (size_t)n * 512 + k];
  else if (k < 528) { int j = k - 512; if (j <= i) v = K[(i - j) * 512 + n]; }
  half_t h, l; split1(v, h, l);
  Wh[idx] = h; Wl[idx] = l;
}

// Z0[c,n] = sum_{j<16} K[15-j,n] * u[16c+j]   (plain f16 out)
__global__ void leaf_kernel(const float* __restrict__ u, const float* __restrict__ K,
                            half_t* __restrict__ Z) {
  __shared__ float us[16];
  int c = blockIdx.x, n = threadIdx.x;
  if (n < 16) us[n] = u[c * 16 + n];
  __syncthreads();
  float acc = 0.f;
#pragma unroll
  for (int j = 0; j < 16; ++j) acc += K[(15 - j) * 512 + n] * us[j];
  Z[(size_t)c * 512 + n] = (half_t)acc;
}

// Xcat cols [512,544): u chunk (16 taps) + zero pad (16), split pair
__global__ void xtail_kernel(const float* __restrict__ u,
                             half_t* __restrict__ Xh, half_t* __restrict__ Xl) {
  int idx = blockIdx.x * 256 + threadIdx.x;    // 4096*32
  int c = idx >> 5, j = idx & 31;
  float v = (j < 16) ? u[c * 16 + j] : 0.f;
  size_t o = (size_t)c * KPAD + 512 + j;
  half_t h, l; split1(v, h, l);
  Xh[o] = h; Xl[o] = l;
}

// dst[(2j)*ldd + n] = src[j*512 + n]; optional lo cleared to 0
__global__ void rowcopy_kernel(const half_t* __restrict__ src,
                               half_t* __restrict__ dh, half_t* __restrict__ dl,
                               long ldd, int nrows) {
  int idx = blockIdx.x * 256 + threadIdx.x;
  int j = idx >> 9, n = idx & 511;
  if (j >= nrows) return;
  size_t d = (size_t)(2 * j) * ldd + n;
  dh[d] = src[(size_t)j * 512 + n];
  if (dl) dl[d] = (half_t)0.f;
}

// -------- chain GEMM: C(512x512 fp32) = A(512x512 fp32) @ B(512x512 fp32) ----
// split-on-the-fly f16 MFMA (3 mfma: hh + hl + lh), batched via grid.z
__global__ __launch_bounds__(256)
void gemm_nn512(const float* __restrict__ A, long sA,
                const float* __restrict__ B, long sB,
                float* __restrict__ C, long sC) {
  __shared__ __align__(16) half_t Ash[64 * 32];
  __shared__ __align__(16) half_t Asl[64 * 32];
  __shared__ __align__(16) half_t Bsh[64 * 32];
  __shared__ __align__(16) half_t Bsl[64 * 32];
  int bz = blockIdx.z;
  A += (size_t)bz * sA; B += (size_t)bz * sB; C += (size_t)bz * sC;
  int m0 = blockIdx.x * 64, n0 = blockIdx.y * 64;
  int tid = threadIdx.x, wave = tid >> 6, lane = tid & 63;
  int wm = (wave & 1) * 32, wn = (wave >> 1) * 32;
  f32x4 acc[2][2], accc[2][2];
  for (int i = 0; i < 2; ++i)
    for (int j = 0; j < 2; ++j) {
      acc[i][j] = (f32x4){0.f, 0.f, 0.f, 0.f};
      accc[i][j] = (f32x4){0.f, 0.f, 0.f, 0.f};
    }
  int r = tid >> 2, sg = tid & 3;
  for (int kt = 0; kt < 16; ++kt) {
    int k0 = kt * 32;
    // A tile: rows straight (K-contiguous)
    {
      const float* ap = A + (size_t)(m0 + r) * 512 + k0 + sg * 8;
      f16x8 hv, lv;
#pragma unroll
      for (int j = 0; j < 8; ++j) { half_t h, l; split1(ap[j], h, l); hv[j] = h; lv[j] = l; }
      *(f16x8*)(Ash + r * 32 + sg * 8) = hv;
      *(f16x8*)(Asl + r * 32 + sg * 8) = lv;
    }
    // B tile: read a column-fragment (8 along k), store n-major [n][k]
    {
      f16x8 hv, lv;
#pragma unroll
      for (int kk = 0; kk < 8; ++kk) {
        float v = B[(size_t)(k0 + sg * 8 + kk) * 512 + n0 + r];
        half_t h, l; split1(v, h, l); hv[kk] = h; lv[kk] = l;
      }
      *(f16x8*)(Bsh + r * 32 + sg * 8) = hv;
      *(f16x8*)(Bsl + r * 32 + sg * 8) = lv;
    }
    __syncthreads();
    int ml = lane & 15, ks = (lane >> 4) * 8;
    f16x8 afh[2], afl[2], bfh[2], bfl[2];
#pragma unroll
    for (int i = 0; i < 2; ++i) {
      afh[i] = *(const f16x8*)(Ash + (wm + i * 16 + ml) * 32 + ks);
      afl[i] = *(const f16x8*)(Asl + (wm + i * 16 + ml) * 32 + ks);
      bfh[i] = *(const f16x8*)(Bsh + (wn + i * 16 + ml) * 32 + ks);
      bfl[i] = *(const f16x8*)(Bsl + (wn + i * 16 + ml) * 32 + ks);
    }
#pragma unroll
    for (int i = 0; i < 2; ++i)
#pragma unroll
      for (int j = 0; j < 2; ++j) {
        acc[i][j] = __builtin_amdgcn_mfma_f32_16x16x32_f16(afh[i], bfh[j], acc[i][j], 0, 0, 0);
        accc[i][j] = __builtin_amdgcn_mfma_f32_16x16x32_f16(afh[i], bfl[j], accc[i][j], 0, 0, 0);
        accc[i][j] = __builtin_amdgcn_mfma_f32_16x16x32_f16(afl[i], bfh[j], accc[i][j], 0, 0, 0);
      }
    __syncthreads();
  }
  int ml = lane & 15, quad = lane >> 4;
  for (int i = 0; i < 2; ++i)
    for (int j = 0; j < 2; ++j)
      for (int rr = 0; rr < 4; ++rr) {
        int gm = m0 + wm + i * 16 + quad * 4 + rr;
        int gn = n0 + wn + j * 16 + ml;
        C[(size_t)gm * 512 + gn] = acc[i][j][rr] + accc[i][j][rr] * INV2048;
      }
}

// -------- sweep GEMM: C(Mx512 f16) = A(Mx512 f16) @ S^T + D; S fp32 512x512 --
// BT arg IS S row-major: C[j,n] = sum_k A[j,k]*S[n,k]. 2 mfma (A plain f16).
__global__ __launch_bounds__(256)
void gemm_nt_sweep(const half_t* __restrict__ A, long ldA,
                   const float* __restrict__ BT,
                   const half_t* __restrict__ D, long ldD,
                   half_t* __restrict__ Ch, half_t* __restrict__ Cl,
                   long ldC, int rScale, int rOff, int M) {
  __shared__ __align__(16) half_t Ash[64 * 32];
  __shared__ __align__(16) half_t Bsh[64 * 32];
  __shared__ __align__(16) half_t Bsl[64 * 32];
  int m0 = blockIdx.x * 64, n0 = blockIdx.y * 64;
  int tid = threadIdx.x, wave = tid >> 6, lane = tid & 63;
  int wm = (wave & 1) * 32, wn = (wave >> 1) * 32;
  f32x4 acc[2][2], accc[2][2];
  for (int i = 0; i < 2; ++i)
    for (int j = 0; j < 2; ++j) {
      acc[i][j] = (f32x4){0.f, 0.f, 0.f, 0.f};
      accc[i][j] = (f32x4){0.f, 0.f, 0.f, 0.f};
    }
  int r = tid >> 2, sg = tid & 3;
  for (int kt = 0; kt < 16; ++kt) {
    int k0 = kt * 32;
    f16x8 av = (f16x8){0, 0, 0, 0, 0, 0, 0, 0};
    if (m0 + r < M) av = *(const f16x8*)(A + (size_t)(m0 + r) * ldA + k0 + sg * 8);
    *(f16x8*)(Ash + r * 32 + sg * 8) = av;
    {
      const float* bp = BT + (size_t)(n0 + r) * 512 + k0 + sg * 8;
      f16x8 hv, lv;
#pragma unroll
      for (int j = 0; j < 8; ++j) { half_t h, l; split1(bp[j], h, l); hv[j] = h; lv[j] = l; }
      *(f16x8*)(Bsh + r * 32 + sg * 8) = hv;
      *(f16x8*)(Bsl + r * 32 + sg * 8) = lv;
    }
    __syncthreads();
    int ml = lane & 15, ks = (lane >> 4) * 8;
    f16x8 af[2], bfh[2], bfl[2];
#pragma unroll
    for (int i = 0; i < 2; ++i) {
      af[i] = *(const f16x8*)(Ash + (wm + i * 16 + ml) * 32 + ks);
      bfh[i] = *(const f16x8*)(Bsh + (wn + i * 16 + ml) * 32 + ks);
      bfl[i] = *(const f16x8*)(Bsl + (wn + i * 16 + ml) * 32 + ks);
    }
#pragma unroll
    for (int i = 0; i < 2; ++i)
#pragma unroll
      for (int j = 0; j < 2; ++j) {
        acc[i][j] = __builtin_amdgcn_mfma_f32_16x16x32_f16(af[i], bfh[j], acc[i][j], 0, 0, 0);
        accc[i][j] = __builtin_amdgcn_mfma_f32_16x16x32_f16(af[i], bfl[j], accc[i][j], 0, 0, 0);
      }
    __syncthreads();
  }
  int ml = lane & 15, quad = lane >> 4;
  for (int i = 0; i < 2; ++i)
    for (int j = 0; j < 2; ++j)
      for (int rr = 0; rr < 4; ++rr) {
        int gm = m0 + wm + i * 16 + quad * 4 + rr;
        int gn = n0 + wn + j * 16 + ml;
        if (gm >= M) continue;
        float v = acc[i][j][rr] + accc[i][j][rr] * INV2048;
        if (D) v += (float)D[(size_t)gm * ldD + gn];
        size_t co = ((size_t)gm * rScale + rOff) * ldC + gn;
        if (Cl) { half_t h, l; split1(v, h, l); Ch[co] = h; Cl[co] = l; }
        else Ch[co] = (half_t)v;
      }
}

// -------- main GEMM: 4096 x 8192 x 544, 128x128 tile, split operands --------
__device__ inline void load_lds16(const half_t* g, half_t* l) {
  __builtin_amdgcn_global_load_lds(
      (const __attribute__((address_space(1))) uint32_t*)g,
      (__attribute__((address_space(3))) uint32_t*)l, 16, 0, 0);
}

__global__ __launch_bounds__(256)
void gemm_main(const half_t* __restrict__ Ah, const half_t* __restrict__ Al,
               const half_t* __restrict__ Bh, const half_t* __restrict__ Bl,
               float* __restrict__ C) {
  __shared__ __align__(16) half_t Ash[128 * 32];
  __shared__ __align__(16) half_t Asl[128 * 32];
  __shared__ __align__(16) half_t Bsh[128 * 32];
  __shared__ __align__(16) half_t Bsl[128 * 32];
  int n0 = blockIdx.x * 128, m0 = blockIdx.y * 128;
  int tid = threadIdx.x, wave = tid >> 6, lane = tid & 63;
  int wm = (wave & 1) * 64, wn = (wave >> 1) * 64;
  f32x4 acc[4][4], accc[4][4];
  for (int i = 0; i < 4; ++i)
    for (int j = 0; j < 4; ++j) {
      acc[i][j] = (f32x4){0.f, 0.f, 0.f, 0.f};
      accc[i][j] = (f32x4){0.f, 0.f, 0.f, 0.f};
    }
  for (int kt = 0; kt < 17; ++kt) {
    int k0 = kt * 32;
#pragma unroll
    for (int q = 0; q < 2; ++q) {
      int chunk = (wave + 4 * q) * 64 + lane;
      int row = chunk >> 2, seg = chunk & 3;
      size_t ga = (size_t)(m0 + row) * KPAD + k0 + seg * 8;
      size_t gb = (size_t)(n0 + row) * KPAD + k0 + seg * 8;
      size_t lo = (size_t)(wave + 4 * q) * 512;
      load_lds16(Ah + ga, Ash + lo);
      load_lds16(Al + ga, Asl + lo);
      load_lds16(Bh + gb, Bsh + lo);
      load_lds16(Bl + gb, Bsl + lo);
    }
    __syncthreads();
    int ml = lane & 15, ks = (lane >> 4) * 8;
    f16x8 afh[4], afl[4], bfh[4], bfl[4];
#pragma unroll
    for (int i = 0; i < 4; ++i) {
      afh[i] = *(const f16x8*)(Ash + (wm + i * 16 + ml) * 32 + ks);
      afl[i] = *(const f16x8*)(Asl + (wm + i * 16 + ml) * 32 + ks);
      bfh[i] = *(const f16x8*)(Bsh + (wn + i * 16 + ml) * 32 + ks);
      bfl[i] = *(const f16x8*)(Bsl + (wn + i * 16 + ml) * 32 + ks);
    }
#pragma unroll
    for (int i = 0; i < 4; ++i)
#pragma unroll
      for (int j = 0; j < 4; ++j) {
        acc[i][j] = __builtin_amdgcn_mfma_f32_16x16x32_f16(afh[i], bfh[j], acc[i][j], 0, 0, 0);
        accc[i][j] = __builtin_amdgcn_mfma_f32_16x16x32_f16(afh[i], bfl[j], accc[i][j], 0, 0, 0);
        accc[i][j] = __builtin_amdgcn_mfma_f32_16x16x32_f16(afl[i], bfh[j], accc[i][j], 0, 0, 0);
      }
    __syncthreads();
  }
  int ml = lane & 15, quad = lane >> 4;
  for (int i = 0; i < 4; ++i)
    for (int j = 0; j < 4; ++j) {
      int gm = m0 + wm + i * 16 + quad * 4;
      int gn = n0 + wn + j * 16 + ml;
      float* o = C + (size_t)gm * 8192 + gn;
      for (int rr = 0; rr < 4; ++rr)
        o[(size_t)rr * 8192] = acc[i][j][rr] + accc[i][j][rr] * INV2048;
    }
}

// ---------------- host orchestration ----------------

extern "C" void kernel_launch(void* const* d_in, const int* in_sizes, int n_in,
                              void* d_out, int out_size, void* d_ws, size_t ws_size,
                              hipStream_t stream) {
  (void)in_sizes; (void)n_in; (void)out_size; (void)ws_size;
  const float* u  = (const float*)d_in[0];   // 65536
  const float* Ab = (const float*)d_in[1];   // 512x512
  const float* Bb = (const float*)d_in[2];   // 512
  const float* x0 = (const float*)d_in[3];   // 512
  float* out = (float*)d_out;                // 65536x512 fp32

  char* base = (char*)d_ws;
  size_t off = 0;
  auto carve = [&](size_t bytes) -> char* {
    char* p = base + off;
    off = (off + bytes + 255) & ~(size_t)255;
    return p;
  };
  float*  Vp  = (float*)carve(16 * MSZ * 4);             // Ab^1..Ab^16 fp32
  float*  Sp  = (float*)carve(11 * MSZ * 4);             // Ab^{16*2^l}, l=1..11
  float*  Kb  = (float*)carve((size_t)16 * 512 * 4);
  half_t* Wh  = (half_t*)carve((size_t)8192 * KPAD * 2);
  half_t* Wl  = (half_t*)carve((size_t)8192 * KPAD * 2);
  half_t* x0h = (half_t*)carve(512 * 2);
  // Total carved: ~46.2 MB. Overlays (stream-ordered, dead-region reuse):
  size_t zoff[13]; zoff[0] = 0;
  for (int l = 0; l < 12; ++l) zoff[l + 1] = zoff[l] + (size_t)(4096 >> l) * 512;
  size_t xoff[13]; xoff[1] = 0;
  for (int l = 1; l < 12; ++l) xoff[l + 1] = xoff[l] + (size_t)(4096 >> l) * 512;
  // Z (8.39 MB) + Xpool (4.19 MB) overlay V[0..14] (15 MB, dead after wcat)
  half_t* Zh  = (half_t*)Vp;
  half_t* Xph = (half_t*)((char*)Vp + ((zoff[12] * 2 + 255) & ~(size_t)255));
  // Xcat pair (8.91 MB) overlays Sp (11.5 MB, dead after down-sweep l=1)
  half_t* Xch = (half_t*)Sp;
  half_t* Xcl = (half_t*)((char*)Sp + (((size_t)4096 * KPAD * 2 + 255) & ~(size_t)255));

  hipLaunchKernelGGL(copy_ab_kernel, dim3(1024), dim3(256), 0, stream, Ab, Vp);
  hipLaunchKernelGGL(cast_x0_kernel, dim3(1), dim3(512), 0, stream, x0, x0h);

  // V-chain by doubling: V_{t+s} = V_t @ V_s, t=1..s, s=1,2,4,8 (batched)
  for (int s = 1; s <= 8; s <<= 1) {
    hipLaunchKernelGGL(gemm_nn512, dim3(8, 8, s), dim3(256), 0, stream,
                       Vp, (long)MSZ,
                       Vp + (size_t)(s - 1) * MSZ, 0L,
                       Vp + (size_t)s * MSZ, (long)MSZ);
  }
  // Squarings: S_1 = (Ab^16)^2, S_l = S_{l-1}^2
  for (int l = 1; l <= 11; ++l) {
    const float* Aop = (l == 1) ? Vp + 15 * MSZ : Sp + (size_t)(l - 2) * MSZ;
    hipLaunchKernelGGL(gemm_nn512, dim3(8, 8, 1), dim3(256), 0, stream,
                       Aop, 0L, Aop, 0L, Sp + (size_t)(l - 1) * MSZ, 0L);
  }

  hipLaunchKernelGGL(kbuild_kernel, dim3(16), dim3(512), 0, stream, Vp, Bb, Kb);
  hipLaunchKernelGGL(wcat_fill_kernel,
                     dim3((unsigned)(((size_t)8192 * KPAD + 255) / 256)), dim3(256), 0, stream,
                     Vp, Kb, Wh, Wl);
  // From here V[0..14] is dead -> Z/Xpool overlay valid.
  hipLaunchKernelGGL(leaf_kernel, dim3(4096), dim3(512), 0, stream, u, Kb, Zh);

  auto Smat = [&](int l) -> const float* {
    return (l == 0) ? (Vp + 15 * MSZ) : (Sp + (size_t)(l - 1) * MSZ);
  };

  // Up-sweep: Z_{l+1}[j] = S_l Z_l[2j] + Z_l[2j+1]
  for (int l = 0; l <= 10; ++l) {
    int M = 1 << (11 - l);
    hipLaunchKernelGGL(gemm_nt_sweep, dim3((unsigned)((M + 63) / 64), 8), dim3(256), 0, stream,
                       Zh + zoff[l], 1024L, Smat(l),
                       Zh + zoff[l] + 512, 1024L,
                       Zh + zoff[l + 1], (half_t*)0, 512L, 1, 0, M);
  }
  // Down-sweep: X_l[2j+1] = S_l X_{l+1}[j] + Z_l[2j]; X_l[2j] = X_{l+1}[j]
  for (int l = 11; l >= 0; --l) {
    int M = 1 << (11 - l);
    const half_t* Xup = (l == 11) ? x0h : Xph + xoff[l + 1];
    half_t* Ch = (l == 0) ? Xch : Xph + xoff[l];
    half_t* Cl = (l == 0) ? Xcl : (half_t*)0;
    long ldC = (l == 0) ? (long)KPAD : 512L;
    if (l == 0) {  // Sp is dead now; Xcat overlay becomes live
      hipLaunchKernelGGL(xtail_kernel, dim3(512), dim3(256), 0, stream, u, Xch, Xcl);
    }
    hipLaunchKernelGGL(gemm_nt_sweep, dim3((unsigned)((M + 63) / 64), 8), dim3(256), 0, stream,
                       Xup, 512L, Smat(l),
                       Zh + zoff[l], 1024L,
                       Ch, Cl, ldC, 2, 1, M);
    hipLaunchKernelGGL(rowcopy_kernel, dim3((unsigned)((M * 512 + 255) / 256)), dim3(256),
                       0, stream, Xup, Ch, Cl, ldC, M);
  }

  // Main GEMM: all 65536x512 outputs, fp32 store.
  hipLaunchKernelGGL(gemm_main, dim3(64, 32), dim3(256), 0, stream, Xch, Xcl, Wh, Wl, out);
}

// Round 4
// 954.939 us; speedup vs baseline: 1.0642x; 1.0642x over previous
//
#include <hip/hip_runtime.h>
#include <cstdint>
#include <cstddef>

// HiPPO x_{k+1} = Ab x_k + b u_k, f[k]=x_{k+1}, L=65536, N=512.
// Chunked scan (C=16, G=4096): one big GEMM F(4096x8192)=Xcat(4096x544)@Wcat,
// chunk states via Blelloch sweep with on-device matrix powers.
// Numerics: split-f16 (Ootomo, scale 2048), fp32 accumulate -> ~22-bit mantissa.
// R4: fragment-native LDS layouts (conflict-free ds_read), coalesced kbuild,
// rowcopy fused into sweep epilogue, split-K=4 atomic chain GEMMs.
// Workspace ~46 MB (round-2 failure was ws overflow; stay under 53 MB).

typedef _Float16 half_t;
typedef _Float16 f16x8 __attribute__((ext_vector_type(8)));
typedef float f32x4 __attribute__((ext_vector_type(4)));

static constexpr int KPAD = 544;               // 512 + 16 u-taps + 16 pad
static constexpr size_t MSZ = (size_t)512 * 512;
static constexpr float INV2048 = 1.f / 2048.f;

__device__ inline void split1(float v, half_t& h, half_t& l) {
  h = (half_t)v;
  l = (half_t)((v - (float)h) * 2048.f);
}

// ---------------- utility kernels ----------------

__global__ void zero_kernel(float4* __restrict__ p, int n4) {
  int i = blockIdx.x * 256 + threadIdx.x;
  if (i < n4) p[i] = make_float4(0.f, 0.f, 0.f, 0.f);
}

__global__ void copy_ab_kernel(const float* __restrict__ Ab, float* __restrict__ V0) {
  int idx = blockIdx.x * 256 + threadIdx.x;    // 262144
  V0[idx] = Ab[idx];
}

__global__ void cast_x0_kernel(const float* __restrict__ x0, half_t* __restrict__ xh) {
  xh[threadIdx.x] = (half_t)x0[threadIdx.x];
}

// K[t,n] = (Ab^t b)[n], t=0..15. One wave per (t,n): coalesced m-stride + reduce.
__global__ void kbuild_kernel(const float* __restrict__ V, const float* __restrict__ b,
                              float* __restrict__ K) {
  int gw = blockIdx.x * 4 + (threadIdx.x >> 6);   // 0..8191
  int lane = threadIdx.x & 63;
  int t = gw >> 9, n = gw & 511;
  if (t == 0) { if (lane == 0) K[n] = b[n]; return; }
  const float* row = V + (size_t)(t - 1) * MSZ + (size_t)n * 512;
  float acc = 0.f;
#pragma unroll
  for (int m = 0; m < 512; m += 64) acc += row[m + lane] * b[m + lane];
#pragma unroll
  for (int s = 32; s; s >>= 1) acc += __shfl_down(acc, s, 64);
  if (lane == 0) K[t * 512 + n] = acc;
}

// WcatT[(i*512+n), k]: k<512 -> Ab^{i+1}[n,k]; 512+j -> (j<=i)?K[i-j,n]:0; pad 0
__global__ void wcat_fill_kernel(const float* __restrict__ V, const float* __restrict__ K,
                                 half_t* __restrict__ Wh, half_t* __restrict__ Wl) {
  size_t idx = (size_t)blockIdx.x * 256 + threadIdx.x;
  if (idx >= (size_t)8192 * KPAD) return;
  int row = (int)(idx / KPAD), k = (int)(idx % KPAD);
  int i = row >> 9, n = row & 511;
  float v = 0.f;
  if (k < 512) v = V[(size_t)i * MSZ + (size_t)n * 512 + k];
  else if (k < 528) { int j = k - 512; if (j <= i) v = K[(i - j) * 512 + n]; }
  half_t h, l; split1(v, h, l);
  Wh[idx] = h; Wl[idx] = l;
}

// Z0[c,n] = sum_{j<16} K[15-j,n] * u[16c+j]   (plain f16 out)
__global__ void leaf_kernel(const float* __restrict__ u, const float* __restrict__ K,
                            half_t* __restrict__ Z) {
  __shared__ float us[16];
  int c = blockIdx.x, n = threadIdx.x;
  if (n < 16) us[n] = u[c * 16 + n];
  __syncthreads();
  float acc = 0.f;
#pragma unroll
  for (int j = 0; j < 16; ++j) acc += K[(15 - j) * 512 + n] * us[j];
  Z[(size_t)c * 512 + n] = (half_t)acc;
}

// Xcat cols [512,544): u chunk (16 taps) + zero pad (16), split pair
__global__ void xtail_kernel(const float* __restrict__ u,
                             half_t* __restrict__ Xh, half_t* __restrict__ Xl) {
  int idx = blockIdx.x * 256 + threadIdx.x;    // 4096*32
  int c = idx >> 5, j = idx & 31;
  float v = (j < 16) ? u[c * 16 + j] : 0.f;
  size_t o = (size_t)c * KPAD + 512 + j;
  half_t h, l; split1(v, h, l);
  Xh[o] = h; Xl[o] = l;
}

// -------- chain GEMM: C += A(512x512 fp32) @ B(512x512 fp32) -----------------
// split-on-the-fly, fragment-native LDS, split-K=4 via grid.z, fp32 atomicAdd.
// grid (8, 8, 4*batch); z = b*4 + kslice. C must be pre-zeroed.
__global__ __launch_bounds__(256)
void gemm_nn512(const float* __restrict__ A, long sA,
                const float* __restrict__ B, long sB,
                float* __restrict__ C, long sC) {
  __shared__ __align__(16) half_t Ash[64 * 32];
  __shared__ __align__(16) half_t Asl[64 * 32];
  __shared__ __align__(16) half_t Bsh[64 * 32];
  __shared__ __align__(16) half_t Bsl[64 * 32];
  int bz = blockIdx.z, bb = bz >> 2, sl = bz & 3;
  A += (size_t)bb * sA; B += (size_t)bb * sB; C += (size_t)bb * sC;
  int m0 = blockIdx.x * 64, n0 = blockIdx.y * 64;
  int tid = threadIdx.x, wave = tid >> 6, lane = tid & 63;
  int wm = (wave & 1) * 32, wn = (wave >> 1) * 32;
  f32x4 acc[2][2], accc[2][2];
  for (int i = 0; i < 2; ++i)
    for (int j = 0; j < 2; ++j) {
      acc[i][j] = (f32x4){0.f, 0.f, 0.f, 0.f};
      accc[i][j] = (f32x4){0.f, 0.f, 0.f, 0.f};
    }
  int rb = tid >> 6, mm = tid & 15, kseg = (tid >> 4) & 3;
  for (int kt = sl * 4; kt < sl * 4 + 4; ++kt) {
    int k0 = kt * 32;
    {  // A: row-major fp32, fragment gather -> linear LDS (tid*16B)
      const float* ap = A + (size_t)(m0 + rb * 16 + mm) * 512 + k0 + kseg * 8;
      f16x8 hv, lv;
#pragma unroll
      for (int j = 0; j < 8; ++j) { half_t h, l; split1(ap[j], h, l); hv[j] = h; lv[j] = l; }
      *(f16x8*)(Ash + tid * 8) = hv;
      *(f16x8*)(Asl + tid * 8) = lv;
    }
    {  // B: column gather (transpose), fragment order
      f16x8 hv, lv;
#pragma unroll
      for (int j = 0; j < 8; ++j) {
        float v = B[(size_t)(k0 + kseg * 8 + j) * 512 + n0 + rb * 16 + mm];
        half_t h, l; split1(v, h, l); hv[j] = h; lv[j] = l;
      }
      *(f16x8*)(Bsh + tid * 8) = hv;
      *(f16x8*)(Bsl + tid * 8) = lv;
    }
    __syncthreads();
    f16x8 afh[2], afl[2], bfh[2], bfl[2];
#pragma unroll
    for (int i = 0; i < 2; ++i) {
      int ra = (wm >> 4) + i, rbn = (wn >> 4) + i;
      afh[i] = *(const f16x8*)(Ash + ra * 512 + lane * 8);
      afl[i] = *(const f16x8*)(Asl + ra * 512 + lane * 8);
      bfh[i] = *(const f16x8*)(Bsh + rbn * 512 + lane * 8);
      bfl[i] = *(const f16x8*)(Bsl + rbn * 512 + lane * 8);
    }
#pragma unroll
    for (int i = 0; i < 2; ++i)
#pragma unroll
      for (int j = 0; j < 2; ++j) {
        acc[i][j] = __builtin_amdgcn_mfma_f32_16x16x32_f16(afh[i], bfh[j], acc[i][j], 0, 0, 0);
        accc[i][j] = __builtin_amdgcn_mfma_f32_16x16x32_f16(afh[i], bfl[j], accc[i][j], 0, 0, 0);
        accc[i][j] = __builtin_amdgcn_mfma_f32_16x16x32_f16(afl[i], bfh[j], accc[i][j], 0, 0, 0);
      }
    __syncthreads();
  }
  int ml = lane & 15, quad = lane >> 4;
  for (int i = 0; i < 2; ++i)
    for (int j = 0; j < 2; ++j)
      for (int rr = 0; rr < 4; ++rr) {
        int gm = m0 + wm + i * 16 + quad * 4 + rr;
        int gn = n0 + wn + j * 16 + ml;
        atomicAdd(&C[(size_t)gm * 512 + gn], acc[i][j][rr] + accc[i][j][rr] * INV2048);
      }
}

// -------- sweep GEMM: C(Mx512) = A(Mx512 f16) @ S^T + D; S fp32 row-major ----
// 2 mfma (A plain f16, S split). Fused even-row copy (down-sweep rowcopy).
__global__ __launch_bounds__(256)
void gemm_nt_sweep(const half_t* __restrict__ A, long ldA,
                   const float* __restrict__ BT,
                   const half_t* __restrict__ D, long ldD,
                   half_t* __restrict__ Ch, half_t* __restrict__ Cl,
                   long ldC, int rScale, int rOff, int doCopy, int M) {
  __shared__ __align__(16) half_t Ash[64 * 32];
  __shared__ __align__(16) half_t Bsh[64 * 32];
  __shared__ __align__(16) half_t Bsl[64 * 32];
  int m0 = blockIdx.x * 64, n0 = blockIdx.y * 64;
  int tid = threadIdx.x, wave = tid >> 6, lane = tid & 63;
  int wm = (wave & 1) * 32, wn = (wave >> 1) * 32;
  f32x4 acc[2][2], accc[2][2];
  for (int i = 0; i < 2; ++i)
    for (int j = 0; j < 2; ++j) {
      acc[i][j] = (f32x4){0.f, 0.f, 0.f, 0.f};
      accc[i][j] = (f32x4){0.f, 0.f, 0.f, 0.f};
    }
  int rb = tid >> 6, mm = tid & 15, kseg = (tid >> 4) & 3;
  for (int kt = 0; kt < 16; ++kt) {
    int k0 = kt * 32;
    int arow = m0 + rb * 16 + mm;
    f16x8 av = (f16x8){0, 0, 0, 0, 0, 0, 0, 0};
    if (arow < M) av = *(const f16x8*)(A + (size_t)arow * ldA + k0 + kseg * 8);
    *(f16x8*)(Ash + tid * 8) = av;
    // fused even-row copy: out[2*arow, k0+kseg*8 ..] = A values (down-sweep)
    if (doCopy && k0 >= n0 && k0 < n0 + 64 && arow < M) {
      size_t co = (size_t)(2 * arow) * ldC + k0 + kseg * 8;
      *(f16x8*)(Ch + co) = av;
      if (Cl) *(f16x8*)(Cl + co) = (f16x8){0, 0, 0, 0, 0, 0, 0, 0};
    }
    {  // S row gather (fp32) -> split fragment
      const float* bp = BT + (size_t)(n0 + rb * 16 + mm) * 512 + k0 + kseg * 8;
      f16x8 hv, lv;
#pragma unroll
      for (int j = 0; j < 8; ++j) { half_t h, l; split1(bp[j], h, l); hv[j] = h; lv[j] = l; }
      *(f16x8*)(Bsh + tid * 8) = hv;
      *(f16x8*)(Bsl + tid * 8) = lv;
    }
    __syncthreads();
    f16x8 af[2], bfh[2], bfl[2];
#pragma unroll
    for (int i = 0; i < 2; ++i) {
      af[i] = *(const f16x8*)(Ash + ((wm >> 4) + i) * 512 + lane * 8);
      bfh[i] = *(const f16x8*)(Bsh + ((wn >> 4) + i) * 512 + lane * 8);
      bfl[i] = *(const f16x8*)(Bsl + ((wn >> 4) + i) * 512 + lane * 8);
    }
#pragma unroll
    for (int i = 0; i < 2; ++i)
#pragma unroll
      for (int j = 0; j < 2; ++j) {
        acc[i][j] = __builtin_amdgcn_mfma_f32_16x16x32_f16(af[i], bfh[j], acc[i][j], 0, 0, 0);
        accc[i][j] = __builtin_amdgcn_mfma_f32_16x16x32_f16(af[i], bfl[j], accc[i][j], 0, 0, 0);
      }
    __syncthreads();
  }
  int ml = lane & 15, quad = lane >> 4;
  for (int i = 0; i < 2; ++i)
    for (int j = 0; j < 2; ++j)
      for (int rr = 0; rr < 4; ++rr) {
        int gm = m0 + wm + i * 16 + quad * 4 + rr;
        int gn = n0 + wn + j * 16 + ml;
        if (gm >= M) continue;
        float v = acc[i][j][rr] + accc[i][j][rr] * INV2048;
        if (D) v += (float)D[(size_t)gm * ldD + gn];
        size_t co = ((size_t)gm * rScale + rOff) * ldC + gn;
        if (Cl) { half_t h, l; split1(v, h, l); Ch[co] = h; Cl[co] = l; }
        else Ch[co] = (half_t)v;
      }
}

// -------- main GEMM: 4096 x 8192 x 544, 128x128 tile, split operands --------
__device__ inline void load_lds16(const half_t* g, half_t* l) {
  __builtin_amdgcn_global_load_lds(
      (const __attribute__((address_space(1))) uint32_t*)g,
      (__attribute__((address_space(3))) uint32_t*)l, 16, 0, 0);
}

__global__ __launch_bounds__(256)
void gemm_main(const half_t* __restrict__ Ah, const half_t* __restrict__ Al,
               const half_t* __restrict__ Bh, const half_t* __restrict__ Bl,
               float* __restrict__ C) {
  __shared__ __align__(16) half_t Ash[128 * 32];
  __shared__ __align__(16) half_t Asl[128 * 32];
  __shared__ __align__(16) half_t Bsh[128 * 32];
  __shared__ __align__(16) half_t Bsl[128 * 32];
  int n0 = blockIdx.x * 128, m0 = blockIdx.y * 128;
  int tid = threadIdx.x, wave = tid >> 6, lane = tid & 63;
  int wm = (wave & 1) * 64, wn = (wave >> 1) * 64;
  int mm = lane & 15, kseg = lane >> 4;
  f32x4 acc[4][4], accc[4][4];
  for (int i = 0; i < 4; ++i)
    for (int j = 0; j < 4; ++j) {
      acc[i][j] = (f32x4){0.f, 0.f, 0.f, 0.f};
      accc[i][j] = (f32x4){0.f, 0.f, 0.f, 0.f};
    }
  for (int kt = 0; kt < 17; ++kt) {
    int k0 = kt * 32;
#pragma unroll
    for (int q = 0; q < 2; ++q) {
      int c = wave + 4 * q;                    // row-block c: rows c*16..c*16+15
      // fragment gather: per-lane global (row=c*16+mm, col=k0+kseg*8),
      // LDS dest linear (base + lane*16B) -> conflict-free ds_read later
      size_t ga = (size_t)(m0 + c * 16 + mm) * KPAD + k0 + kseg * 8;
      size_t gb = (size_t)(n0 + c * 16 + mm) * KPAD + k0 + kseg * 8;
      size_t lo = (size_t)c * 512;
      load_lds16(Ah + ga, Ash + lo);
      load_lds16(Al + ga, Asl + lo);
      load_lds16(Bh + gb, Bsh + lo);
      load_lds16(Bl + gb, Bsl + lo);
    }
    __syncthreads();
    f16x8 afh[4], afl[4], bfh[4], bfl[4];
#pragma unroll
    for (int i = 0; i < 4; ++i) {
      int ra = (wm >> 4) + i, rbn = (wn >> 4) + i;
      afh[i] = *(const f16x8*)(Ash + ra * 512 + lane * 8);
      afl[i] = *(const f16x8*)(Asl + ra * 512 + lane * 8);
      bfh[i] = *(const f16x8*)(Bsh + rbn * 512 + lane * 8);
      bfl[i] = *(const f16x8*)(Bsl + rbn * 512 + lane * 8);
    }
#pragma unroll
    for (int i = 0; i < 4; ++i)
#pragma unroll
      for (int j = 0; j < 4; ++j) {
        acc[i][j] = __builtin_amdgcn_mfma_f32_16x16x32_f16(afh[i], bfh[j], acc[i][j], 0, 0, 0);
        accc[i][j] = __builtin_amdgcn_mfma_f32_16x16x32_f16(afh[i], bfl[j], accc[i][j], 0, 0, 0);
        accc[i][j] = __builtin_amdgcn_mfma_f32_16x16x32_f16(afl[i], bfh[j], accc[i][j], 0, 0, 0);
      }
    __syncthreads();
  }
  int ml = lane & 15, quad = lane >> 4;
  for (int i = 0; i < 4; ++i)
    for (int j = 0; j < 4; ++j) {
      int gm = m0 + wm + i * 16 + quad * 4;
      int gn = n0 + wn + j * 16 + ml;
      float* o = C + (size_t)gm * 8192 + gn;
      for (int rr = 0; rr < 4; ++rr)
        o[(size_t)rr * 8192] = acc[i][j][rr] + accc[i][j][rr] * INV2048;
    }
}

// ---------------- host orchestration ----------------

extern "C" void kernel_launch(void* const* d_in, const int* in_sizes, int n_in,
                              void* d_out, int out_size, void* d_ws, size_t ws_size,
                              hipStream_t stream) {
  (void)in_sizes; (void)n_in; (void)out_size; (void)ws_size;
  const float* u  = (const float*)d_in[0];   // 65536
  const float* Ab = (const float*)d_in[1];   // 512x512
  const float* Bb = (const float*)d_in[2];   // 512
  const float* x0 = (const float*)d_in[3];   // 512
  float* out = (float*)d_out;                // 65536x512 fp32

  char* base = (char*)d_ws;
  size_t off = 0;
  auto carve = [&](size_t bytes) -> char* {
    char* p = base + off;
    off = (off + bytes + 255) & ~(size_t)255;
    return p;
  };
  float*  Vp  = (float*)carve(16 * MSZ * 4);             // Ab^1..Ab^16 fp32
  float*  Sp  = (float*)carve(11 * MSZ * 4);             // Ab^{16*2^l}, l=1..11
  float*  Kb  = (float*)carve((size_t)16 * 512 * 4);
  half_t* Wh  = (half_t*)carve((size_t)8192 * KPAD * 2);
  half_t* Wl  = (half_t*)carve((size_t)8192 * KPAD * 2);
  half_t* x0h = (half_t*)carve(512 * 2);
  // Overlays (stream-ordered dead-region reuse):
  size_t zoff[13]; zoff[0] = 0;
  for (int l = 0; l < 12; ++l) zoff[l + 1] = zoff[l] + (size_t)(4096 >> l) * 512;
  size_t xoff[13]; xoff[1] = 0;
  for (int l = 1; l < 12; ++l) xoff[l + 1] = xoff[l] + (size_t)(4096 >> l) * 512;
  // Z + Xpool overlay V[0..14] (dead after wcat_fill)
  half_t* Zh  = (half_t*)Vp;
  half_t* Xph = (half_t*)((char*)Vp + ((zoff[12] * 2 + 255) & ~(size_t)255));
  // Xcat pair overlays Sp (dead after down-sweep l=1)
  half_t* Xch = (half_t*)Sp;
  half_t* Xcl = (half_t*)((char*)Sp + (((size_t)4096 * KPAD * 2 + 255) & ~(size_t)255));

  // Zero chain outputs (Vp slots 1..15 + Sp, contiguous 26*MSZ fp32) for atomics
  {
    int n4 = (int)(26 * MSZ / 4);
    hipLaunchKernelGGL(zero_kernel, dim3((n4 + 255) / 256), dim3(256), 0, stream,
                       (float4*)(Vp + MSZ), n4);
  }
  hipLaunchKernelGGL(copy_ab_kernel, dim3(1024), dim3(256), 0, stream, Ab, Vp);
  hipLaunchKernelGGL(cast_x0_kernel, dim3(1), dim3(512), 0, stream, x0, x0h);

  // V-chain by doubling: V_{t+s} = V_t @ V_s, t=1..s, s=1,2,4,8 (batched, split-K)
  for (int s = 1; s <= 8; s <<= 1) {
    hipLaunchKernelGGL(gemm_nn512, dim3(8, 8, 4 * s), dim3(256), 0, stream,
                       Vp, (long)MSZ,
                       Vp + (size_t)(s - 1) * MSZ, 0L,
                       Vp + (size_t)s * MSZ, (long)MSZ);
  }
  // Squarings: S_1 = (Ab^16)^2, S_l = S_{l-1}^2
  for (int l = 1; l <= 11; ++l) {
    const float* Aop = (l == 1) ? Vp + 15 * MSZ : Sp + (size_t)(l - 2) * MSZ;
    hipLaunchKernelGGL(gemm_nn512, dim3(8, 8, 4), dim3(256), 0, stream,
                       Aop, 0L, Aop, 0L, Sp + (size_t)(l - 1) * MSZ, 0L);
  }

  hipLaunchKernelGGL(kbuild_kernel, dim3(2048), dim3(256), 0, stream, Vp, Bb, Kb);
  hipLaunchKernelGGL(wcat_fill_kernel,
                     dim3((unsigned)(((size_t)8192 * KPAD + 255) / 256)), dim3(256), 0, stream,
                     Vp, Kb, Wh, Wl);
  // From here V[0..14] is dead -> Z/Xpool overlay valid.
  hipLaunchKernelGGL(leaf_kernel, dim3(4096), dim3(512), 0, stream, u, Kb, Zh);

  auto Smat = [&](int l) -> const float* {
    return (l == 0) ? (Vp + 15 * MSZ) : (Sp + (size_t)(l - 1) * MSZ);
  };

  // Up-sweep: Z_{l+1}[j] = S_l Z_l[2j] + Z_l[2j+1]
  for (int l = 0; l <= 10; ++l) {
    int M = 1 << (11 - l);
    hipLaunchKernelGGL(gemm_nt_sweep, dim3((unsigned)((M + 63) / 64), 8), dim3(256), 0, stream,
                       Zh + zoff[l], 1024L, Smat(l),
                       Zh + zoff[l] + 512, 1024L,
                       Zh + zoff[l + 1], (half_t*)0, 512L, 1, 0, 0, M);
  }
  // Down-sweep: X_l[2j+1] = S_l X_{l+1}[j] + Z_l[2j]; X_l[2j] = X_{l+1}[j] (fused)
  for (int l = 11; l >= 0; --l) {
    int M = 1 << (11 - l);
    const half_t* Xup = (l == 11) ? x0h : Xph + xoff[l + 1];
    half_t* Ch = (l == 0) ? Xch : Xph + xoff[l];
    half_t* Cl = (l == 0) ? Xcl : (half_t*)0;
    long ldC = (l == 0) ? (long)KPAD : 512L;
    if (l == 0) {  // Sp is dead now; Xcat overlay becomes live
      hipLaunchKernelGGL(xtail_kernel, dim3(512), dim3(256), 0, stream, u, Xch, Xcl);
    }
    hipLaunchKernelGGL(gemm_nt_sweep, dim3((unsigned)((M + 63) / 64), 8), dim3(256), 0, stream,
                       Xup, 512L, Smat(l),
                       Zh + zoff[l], 1024L,
                       Ch, Cl, ldC, 2, 1, 1, M);
  }

  // Main GEMM: all 65536x512 outputs, fp32 store.
  hipLaunchKernelGGL(gemm_main, dim3(64, 32), dim3(256), 0, stream, Xch, Xcl, Wh, Wl, out);
}